// Round 4
// baseline (207.927 us; speedup 1.0000x reference)
//
#include <hip/hip_runtime.h>
#include <math.h>
#include <stdint.h>

// MultipleTopoTreeLoss = mean over 32 (sample,chunk) pairs of sum of squared
// Euclidean-MST edge lengths of 1024 standardized 3-D points.
//
// Boruvka (<=10 rounds, each fully parallel).  Round-3 post-mortem: ~50us of
// launch gaps across 22 dispatches + per-round LDS restaging + LDS-pipe-bound
// scan.  This round: ONE persistent kernel (256 blocks = 32 samples x 8,
// all co-resident on 256 CUs), per-sample 8-block sense-reversing barrier
// (agent-scope atomics; samples independent -> no grid sync), points staged
// in LDS once, comp labels refreshed as packed 4xu16, scan = 4 nodes/thread
// so each ds_read_b128 feeds 4 evals, half-wave shuffle pre-reduction before
// LDS atomicMin.  All cross-block traffic uses agent-scope atomics (per-XCD
// L2s are not coherent).
//
//   scan:    per node, nearest node in a different component; per-component
//            min of u64 key = d2bits<<32 | min(i,j)<<10 | max(i,j).
//            Symmetric distinct keys => total edge order => hooking graph has
//            only 2-cycles; dedupe by key equality.  (Logic passed r2/r3.)
//   combine: hook, add weight once per unique edge, break 2-cycles, chase to
//            roots, relabel, count comps; done by the sample's part-0 block.

#define NSAMP   32
#define NPTS    1024
#define SBLK    8          // blocks per sample
#define NPN     128        // nodes per block
#define TPB     1024
#define MAXRD   12         // Boruvka needs <=10; safety margin
#define EMPTY64 0xFFFFFFFFFFFFFFFFull

typedef unsigned long long u64;

__device__ __forceinline__ u64 aload64(const u64* p) {
  return __hip_atomic_load(p, __ATOMIC_RELAXED, __HIP_MEMORY_SCOPE_AGENT);
}
__device__ __forceinline__ void astore64(u64* p, u64 v) {
  __hip_atomic_store(p, v, __ATOMIC_RELAXED, __HIP_MEMORY_SCOPE_AGENT);
}
__device__ __forceinline__ int aload32(const int* p) {
  return __hip_atomic_load(p, __ATOMIC_RELAXED, __HIP_MEMORY_SCOPE_AGENT);
}
__device__ __forceinline__ void astore32(int* p, int v) {
  __hip_atomic_store(p, v, __ATOMIC_RELAXED, __HIP_MEMORY_SCOPE_AGENT);
}

// sense-reversing barrier among the SBLK blocks of one sample
__device__ __forceinline__ void sbar(int* cnt, int* sense, int& ls) {
  __syncthreads();
  if (threadIdx.x == 0) {
    ls ^= 1;
    const int prev =
        __hip_atomic_fetch_add(cnt, 1, __ATOMIC_ACQ_REL, __HIP_MEMORY_SCOPE_AGENT);
    if (prev == SBLK - 1) {
      astore32(cnt, 0);  // reset before release of sense
      __hip_atomic_store(sense, ls, __ATOMIC_RELEASE, __HIP_MEMORY_SCOPE_AGENT);
    } else {
      while (__hip_atomic_load(sense, __ATOMIC_ACQUIRE,
                               __HIP_MEMORY_SCOPE_AGENT) != ls) {
        __builtin_amdgcn_s_sleep(4);
      }
    }
  }
  __syncthreads();
}

__device__ __forceinline__ float block_sum256(float v, volatile float* red) {
#pragma unroll
  for (int off = 32; off > 0; off >>= 1) v += __shfl_xor(v, off, 64);
  __syncthreads();
  if ((threadIdx.x & 63) == 0) red[threadIdx.x >> 6] = v;
  __syncthreads();
  return red[0] + red[1] + red[2] + red[3];
}

__device__ __forceinline__ float block_sum1024(float v, volatile float* red) {
#pragma unroll
  for (int off = 32; off > 0; off >>= 1) v += __shfl_xor(v, off, 64);
  __syncthreads();
  if ((threadIdx.x & 63) == 0) red[threadIdx.x >> 6] = v;
  __syncthreads();
  float r = 0.f;
#pragma unroll
  for (int k = 0; k < 16; ++k) r += red[k];
  return r;
}

// ---- Phase 0: standardize points, init all persistent-kernel state ---------
__global__ __launch_bounds__(256) void norm_init_kernel(
    const float* __restrict__ r, float4* __restrict__ pts4,
    u64* __restrict__ winner, u64* __restrict__ comp_packed,
    int* __restrict__ ncomp, int* __restrict__ bar) {
  const int s = blockIdx.x;             // 0..31
  const int b = s >> 1, c = s & 1;
  const int tid = threadIdx.x;
  const float* __restrict__ base = r + ((size_t)b * 2 + c) * (NPTS * 3);
  __shared__ float red[4];

  float x[4], y[4], z[4];
  float sx = 0.f, sy = 0.f, sz = 0.f;
#pragma unroll
  for (int k = 0; k < 4; ++k) {
    const int i = k * 256 + tid;
    x[k] = base[i * 3 + 0]; y[k] = base[i * 3 + 1]; z[k] = base[i * 3 + 2];
    sx += x[k]; sy += y[k]; sz += z[k];
  }
  sx = block_sum256(sx, red); sy = block_sum256(sy, red); sz = block_sum256(sz, red);
  const float mx = sx * (1.f / NPTS), my = sy * (1.f / NPTS), mz = sz * (1.f / NPTS);

  float vx = 0.f, vy = 0.f, vz = 0.f;
#pragma unroll
  for (int k = 0; k < 4; ++k) {
    const float dx = x[k] - mx, dy = y[k] - my, dz = z[k] - mz;
    vx += dx * dx; vy += dy * dy; vz += dz * dz;
  }
  vx = block_sum256(vx, red); vy = block_sum256(vy, red); vz = block_sum256(vz, red);
  const float ix = 1.f / (sqrtf(vx * (1.f / NPTS)) + 1e-8f);
  const float iy = 1.f / (sqrtf(vy * (1.f / NPTS)) + 1e-8f);
  const float iz = 1.f / (sqrtf(vz * (1.f / NPTS)) + 1e-8f);

#pragma unroll
  for (int k = 0; k < 4; ++k) {
    const int i = k * 256 + tid;
    pts4[s * NPTS + i] =
        make_float4((x[k] - mx) * ix, (y[k] - my) * iy, (z[k] - mz) * iz, 0.f);
    winner[s * NPTS + i] = EMPTY64;
  }
  // identity comp labels, packed 4 x u16 per u64
  {
    const u64 n0 = (u64)(4 * tid);
    comp_packed[s * 256 + tid] =
        n0 | ((n0 + 1) << 16) | ((n0 + 2) << 32) | ((n0 + 3) << 48);
  }
  if (tid == 0) { ncomp[s] = NPTS; bar[s * 16] = 0; bar[s * 16 + 8] = 0; }
}

// ---- Persistent Boruvka: all rounds in one launch --------------------------
__global__ __launch_bounds__(TPB) void boruvka_kernel(
    const float4* __restrict__ pts4, u64* __restrict__ winner,
    u64* __restrict__ comp_packed, int* __restrict__ ncomp,
    int* __restrict__ bar, float* __restrict__ out) {
  const int s    = blockIdx.x >> 3;     // sample
  const int part = blockIdx.x & 7;      // block within sample
  const int tid  = threadIdx.x;

  __shared__ float4 P[NPTS];            // 16 KiB: points, .w = comp bits
  __shared__ u64 Wl[NPTS];              // 8 KiB: scan pre-reduce / combine W
  __shared__ short parentL[NPTS];       // 2 KiB
  __shared__ short rootL[NPTS];         // 2 KiB
  __shared__ float red[16];
  __shared__ int bcast;

  u64* __restrict__ gw  = winner + s * NPTS;
  u64* __restrict__ gcp = comp_packed + s * 256;
  int* bcnt = bar + s * 16;
  int* bsen = bar + s * 16 + 8;

  // stage points ONCE (kernel boundary makes norm_init's writes visible)
  P[tid] = pts4[s * NPTS + tid];

  int   ls    = 0;     // barrier sense (thread 0's copy is the live one)
  float total = 0.f;   // part-0 block accumulates MST weight across rounds

  const int g  = tid >> 5;              // node group 0..31
  const int sl = tid & 31;              // candidate sub-lane 0..31
  const int n0 = part * NPN + g * 4;    // first of this thread's 4 nodes

  for (int rd = 0; rd < MAXRD; ++rd) {
    // ---- refresh comp labels into P[].w, clear Wl ----
    Wl[tid] = EMPTY64;
    if (tid < 256) {
      const u64 cp = aload64(&gcp[tid]);
      P[tid * 4 + 0].w = __uint_as_float((unsigned)(cp & 0xFFFFu));
      P[tid * 4 + 1].w = __uint_as_float((unsigned)((cp >> 16) & 0xFFFFu));
      P[tid * 4 + 2].w = __uint_as_float((unsigned)((cp >> 32) & 0xFFFFu));
      P[tid * 4 + 3].w = __uint_as_float((unsigned)((cp >> 48) & 0xFFFFu));
    }
    __syncthreads();

    // ---- scan: 4 nodes x 32 candidates per thread ----
    float mex[4], mey[4], mez[4]; unsigned mc[4];
#pragma unroll
    for (int n = 0; n < 4; ++n) {
      const float4 p = P[n0 + n];
      mex[n] = p.x; mey[n] = p.y; mez[n] = p.z; mc[n] = __float_as_uint(p.w);
    }
    float bd[4]; int bj[4];
#pragma unroll
    for (int n = 0; n < 4; ++n) { bd[n] = INFINITY; bj[n] = n0 + n; }
#pragma unroll 4
    for (int jj = 0; jj < 32; ++jj) {
      const int j = sl + (jj << 5);     // lanes: 32 consecutive float4s x2
      const float4 q = P[j];
      const unsigned qc = __float_as_uint(q.w);
#pragma unroll
      for (int n = 0; n < 4; ++n) {
        const float dx = mex[n] - q.x, dy = mey[n] - q.y, dz = mez[n] - q.z;
        float d2 = dx * dx + dy * dy + dz * dz;
        d2 = (qc == mc[n]) ? INFINITY : d2;
        if (d2 < bd[n]) { bd[n] = d2; bj[n] = j; }
      }
    }
    // reduce the 32 sub-lanes of each node group (stays within half-wave)
#pragma unroll
    for (int off = 16; off > 0; off >>= 1) {
#pragma unroll
      for (int n = 0; n < 4; ++n) {
        const float od = __shfl_xor(bd[n], off, 64);
        const int   oj = __shfl_xor(bj[n], off, 64);
        if (od < bd[n] || (od == bd[n] && oj < bj[n])) { bd[n] = od; bj[n] = oj; }
      }
    }
    if (sl == 0) {
#pragma unroll
      for (int n = 0; n < 4; ++n) {
        if (bd[n] < INFINITY) {
          const int node = n0 + n, j = bj[n];
          const unsigned a = (unsigned)(node < j ? node : j);
          const unsigned b = (unsigned)(node < j ? j : node);
          const u64 key =
              ((u64)__float_as_uint(bd[n]) << 32) | (a << 10) | b;
          atomicMin(&Wl[mc[n]], key);   // <=8 LDS atomics per wave
        }
      }
    }
    __syncthreads();
    // flush local winners to global (<=128 non-empty slots)
    {
      const u64 w = Wl[tid];
      if (w != EMPTY64) atomicMin(&gw[tid], w);
    }
    sbar(bcnt, bsen, ls);               // barrier A: all scans visible

    if (part == 0) {
      // ---- combine (this sample's part-0 block only) ----
      const int c = tid;
      Wl[c] = aload64(&gw[c]);
      astore64(&gw[c], EMPTY64);        // reset for next round
      __syncthreads();
      const u64 w = Wl[c];
      short par = (short)c;
      float wsum = 0.f;
      if (w != EMPTY64) {
        const int pmin = (int)((w >> 10) & 1023u);
        const int pmax = (int)(w & 1023u);
        const int cmin = (int)__float_as_uint(P[pmin].w);
        const int cmax = (int)__float_as_uint(P[pmax].w);
        const int c2 = (cmin == c) ? cmax : cmin;
        par = (short)c2;
        const bool dup = (Wl[c2] == w); // same undirected edge <=> same key
        if (!dup || c < c2) wsum += __uint_as_float((unsigned)(w >> 32));
      }
      parentL[c] = par;
      __syncthreads();
      { // break 2-cycles: smaller index becomes root
        const int p = parentL[c];
        if (p != c && parentL[p] == c && c < p) parentL[c] = (short)c;
      }
      __syncthreads();
      { // chase to roots (forest after 2-cycle break)
        int p = parentL[c];
        for (int it = 0; it < 1024 && parentL[p] != p; ++it) p = parentL[p];
        rootL[c] = (short)p;
      }
      __syncthreads();
      const int nc = rootL[(int)__float_as_uint(P[c].w)];
      const int cnt = (nc == c) ? 1 : 0;
      __syncthreads();
      parentL[c] = (short)nc;           // reuse as per-node new comp
      __syncthreads();
      if (tid < 256) {
        const u64 cp = (u64)(unsigned short)parentL[tid * 4 + 0]
                     | ((u64)(unsigned short)parentL[tid * 4 + 1] << 16)
                     | ((u64)(unsigned short)parentL[tid * 4 + 2] << 32)
                     | ((u64)(unsigned short)parentL[tid * 4 + 3] << 48);
        astore64(&gcp[tid], cp);
      }
      const float ws_ = block_sum1024(wsum, red);
      const float fc  = block_sum1024((float)cnt, red);
      total += ws_;
      if (tid == 0) {
        astore32(&ncomp[s], (int)fc);
        if ((int)fc == 1) atomicAdd(out, total * (1.f / NSAMP));
      }
    }
    sbar(bcnt, bsen, ls);               // barrier B: combine visible

    if (tid == 0) bcast = aload32(&ncomp[s]);
    __syncthreads();
    if (bcast == 1) break;              // uniform across the sample's blocks
  }
}

extern "C" void kernel_launch(void* const* d_in, const int* in_sizes, int n_in,
                              void* d_out, int out_size, void* d_ws, size_t ws_size,
                              hipStream_t stream) {
  const float* r = (const float*)d_in[0];
  float* out = (float*)d_out;
  (void)in_sizes; (void)n_in; (void)out_size; (void)ws_size;

  char* ws = (char*)d_ws;               // < 1 MB used
  float4* pts4       = (float4*)ws;                   // 512 KiB
  u64*    winner     = (u64*)(ws + 524288);           // 256 KiB
  u64*    comp_packed= (u64*)(ws + 786432);           //  64 KiB
  int*    ncomp      = (int*)(ws + 851968);           // 128 B
  int*    bar        = (int*)(ws + 853504);           // 32 x 64 B

  hipMemsetAsync(out, 0, sizeof(float), stream);

  norm_init_kernel<<<dim3(NSAMP), dim3(256), 0, stream>>>(
      r, pts4, winner, comp_packed, ncomp, bar);
  boruvka_kernel<<<dim3(NSAMP * SBLK), dim3(TPB), 0, stream>>>(
      pts4, winner, comp_packed, ncomp, bar, out);
}

// Round 5
// 179.860 us; speedup vs baseline: 1.1560x; 1.1560x over previous
//
#include <hip/hip_runtime.h>
#include <math.h>
#include <stdint.h>

// MultipleTopoTreeLoss = mean over 32 (sample,chunk) pairs of sum of squared
// Euclidean-MST edge lengths of 1024 standardized 3-D points.  Boruvka.
//
// Round-4 post-mortem: persistent kernel regressed because (1) a sample's 8
// blocks were spread across all 8 XCDs -> every barrier/atomic ping-ponged
// across non-coherent L2s, (2) combine ran on 1 block while 7 spun, (3) two
// barriers/round.  This round:
//   - part = blockIdx>>5, s = blockIdx&31  -> all 8 blocks of a sample land
//     on ONE XCD (b%8 == s%8 for b = s+32k); barrier + winner lines L2-local.
//   - combine is computed REDUNDANTLY by all 8 blocks from the global winner
//     table (1 agent load/thread) -> no idle spin, no global comp array, and
//     the exit test (ncomp==1) is block-local and uniform.
//   - ONE barrier/round: winner tables double-buffered by round parity, keys
//     carry tag=(15-rd) in bits 63:60 (decreasing -> current round always
//     wins atomicMin over stale entries; no per-round clears).
//   - norm/standardization folded in (redundant per block): launches are
//     1 tiny memset + 1 kernel.
// Key = tag<<60 | d2bits<<20 | min(i,j)<<10 | max(i,j): symmetric, distinct
// per edge => total order => hooking graph has only 2-cycles; dedupe by key
// equality (logic unchanged from r2-r4, all passed absmax 0).

#define NSAMP   32
#define NPTS    1024
#define SBLK    8          // blocks per sample
#define NPN     128        // nodes per block
#define TPB     1024
#define MAXRD   11         // Boruvka needs <=10
#define EMPTY64 0xFFFFFFFFFFFFFFFFull

typedef unsigned long long u64;

__device__ __forceinline__ u64 aload64(const u64* p) {
  return __hip_atomic_load(p, __ATOMIC_RELAXED, __HIP_MEMORY_SCOPE_AGENT);
}
__device__ __forceinline__ void astore64(u64* p, u64 v) {
  __hip_atomic_store(p, v, __ATOMIC_RELAXED, __HIP_MEMORY_SCOPE_AGENT);
}

// sense-reversing barrier among the SBLK blocks of one sample (XCD-local)
__device__ __forceinline__ void sbar(int* cnt, int* sense, int& ls) {
  __syncthreads();
  if (threadIdx.x == 0) {
    ls ^= 1;
    const int prev =
        __hip_atomic_fetch_add(cnt, 1, __ATOMIC_ACQ_REL, __HIP_MEMORY_SCOPE_AGENT);
    if (prev == SBLK - 1) {
      __hip_atomic_store(cnt, 0, __ATOMIC_RELAXED, __HIP_MEMORY_SCOPE_AGENT);
      __hip_atomic_store(sense, ls, __ATOMIC_RELEASE, __HIP_MEMORY_SCOPE_AGENT);
    } else {
      while (__hip_atomic_load(sense, __ATOMIC_ACQUIRE,
                               __HIP_MEMORY_SCOPE_AGENT) != ls) {
        __builtin_amdgcn_s_sleep(2);
      }
    }
  }
  __syncthreads();
}

// sum two values across the 1024-thread block (deterministic order)
__device__ __forceinline__ void block_sum2(float& a, float& b, float* red) {
#pragma unroll
  for (int off = 32; off > 0; off >>= 1) {
    a += __shfl_xor(a, off, 64);
    b += __shfl_xor(b, off, 64);
  }
  __syncthreads();
  const int wid = threadIdx.x >> 6;
  if ((threadIdx.x & 63) == 0) { red[wid * 2] = a; red[wid * 2 + 1] = b; }
  __syncthreads();
  float ra = 0.f, rb = 0.f;
#pragma unroll
  for (int k = 0; k < 16; ++k) { ra += red[k * 2]; rb += red[k * 2 + 1]; }
  a = ra; b = rb;
}

__global__ __launch_bounds__(TPB) void topo_kernel(
    const float* __restrict__ r, u64* __restrict__ gw0, u64* __restrict__ gw1,
    int* __restrict__ bar, float* __restrict__ acc, int* __restrict__ done,
    float* __restrict__ out) {
  const int s    = blockIdx.x & 31;   // sample: same-XCD for all its blocks
  const int part = blockIdx.x >> 5;   // 0..7
  const int tid  = threadIdx.x;

  __shared__ float4 P[NPTS];          // 16 KiB: points, .w = comp label bits
  __shared__ u64 Wl[NPTS];            // 8 KiB: per-comp winner (scan+combine)
  __shared__ short parentL[NPTS];     // 2 KiB
  __shared__ short rootL[NPTS];       // 2 KiB
  __shared__ float red[32];

  int* bcnt = bar + s * 32;
  int* bsen = bar + s * 32 + 16;
  u64* __restrict__ gws0 = gw0 + s * NPTS;
  u64* __restrict__ gws1 = gw1 + s * NPTS;

  // ---- load + standardize (redundant per block; bitwise-identical) ----
  const float* __restrict__ base = r + (size_t)s * (NPTS * 3);
  const float px = base[tid * 3 + 0];
  const float py = base[tid * 3 + 1];
  const float pz = base[tid * 3 + 2];
  float sx = px, sy = py, sz = pz, dm = 0.f;
  block_sum2(sx, sy, red);
  block_sum2(sz, dm, red);
  const float mx = sx * (1.f / NPTS), my = sy * (1.f / NPTS), mz = sz * (1.f / NPTS);
  const float ex = px - mx, ey = py - my, ez = pz - mz;
  float vx = ex * ex, vy = ey * ey, vz = ez * ez;
  dm = 0.f;
  block_sum2(vx, vy, red);
  block_sum2(vz, dm, red);
  const float ix = 1.f / (sqrtf(vx * (1.f / NPTS)) + 1e-8f);
  const float iy = 1.f / (sqrtf(vy * (1.f / NPTS)) + 1e-8f);
  const float iz = 1.f / (sqrtf(vz * (1.f / NPTS)) + 1e-8f);
  P[tid] = make_float4(ex * ix, ey * iy, ez * iz, __uint_as_float((unsigned)tid));

  // ---- one-time clear of both winner buffers (own 1/8 slice) ----
  if (tid < NPN) {
    astore64(&gws0[part * NPN + tid], EMPTY64);
    astore64(&gws1[part * NPN + tid], EMPTY64);
  }
  int ls = 0;
  sbar(bcnt, bsen, ls);               // clears visible before any flush

  float total = 0.f;
  const int g  = tid >> 5;            // node group 0..31
  const int sl = tid & 31;            // candidate sub-lane 0..31
  const int n0 = part * NPN + g * 4;  // first of this thread's 4 nodes

  for (int rd = 0; rd < MAXRD; ++rd) {
    u64* __restrict__ gwc = (rd & 1) ? gws1 : gws0;
    const u64 tag = (u64)(15 - rd) << 60;   // decreasing: current wins min

    Wl[tid] = EMPTY64;
    __syncthreads();

    // ---- scan: 4 nodes x 32 candidates per thread ----
    float mex[4], mey[4], mez[4]; unsigned mc[4];
#pragma unroll
    for (int n = 0; n < 4; ++n) {
      const float4 p = P[n0 + n];
      mex[n] = p.x; mey[n] = p.y; mez[n] = p.z; mc[n] = __float_as_uint(p.w);
    }
    float bd[4]; int bj[4];
#pragma unroll
    for (int n = 0; n < 4; ++n) { bd[n] = INFINITY; bj[n] = n0 + n; }
#pragma unroll 8
    for (int jj = 0; jj < 32; ++jj) {
      const int j = sl + (jj << 5);
      const float4 q = P[j];          // lanes l, l+32 share addr: broadcast
      const unsigned qc = __float_as_uint(q.w);
#pragma unroll
      for (int n = 0; n < 4; ++n) {
        const float dx = mex[n] - q.x, dy = mey[n] - q.y, dz = mez[n] - q.z;
        float d2 = dx * dx + dy * dy + dz * dz;
        d2 = (qc == mc[n]) ? INFINITY : d2;
        if (d2 < bd[n]) { bd[n] = d2; bj[n] = j; }
      }
    }
#pragma unroll
    for (int off = 16; off > 0; off >>= 1) {    // reduce 32 sub-lanes
#pragma unroll
      for (int n = 0; n < 4; ++n) {
        const float od = __shfl_xor(bd[n], off, 64);
        const int   oj = __shfl_xor(bj[n], off, 64);
        if (od < bd[n] || (od == bd[n] && oj < bj[n])) { bd[n] = od; bj[n] = oj; }
      }
    }
    if (sl == 0) {
#pragma unroll
      for (int n = 0; n < 4; ++n) {
        if (bd[n] < INFINITY) {
          const int node = n0 + n, j = bj[n];
          const unsigned a = (unsigned)(node < j ? node : j);
          const unsigned b = (unsigned)(node < j ? j : node);
          const u64 key = tag | ((u64)__float_as_uint(bd[n]) << 20)
                        | (a << 10) | b;
          atomicMin(&Wl[mc[n]], key);
        }
      }
    }
    __syncthreads();
    { // flush local winners to the round's global buffer
      const u64 w = Wl[tid];
      if (w != EMPTY64) atomicMin(&gwc[tid], w);
    }
    sbar(bcnt, bsen, ls);             // all flushes of this round visible

    // ---- combine, computed redundantly by every block ----
    const u64 w = aload64(&gwc[tid]); // tid == comp slot (XCD-local L2 hit)
    Wl[tid] = w;
    __syncthreads();
    const unsigned curtag = (unsigned)(15 - rd);
    float wsum = 0.f;
    short par = (short)tid;
    if ((unsigned)(w >> 60) == curtag) {
      const int pmin = (int)((w >> 10) & 1023u);
      const int pmax = (int)(w & 1023u);
      const int cmin = (int)__float_as_uint(P[pmin].w);
      const int cmax = (int)__float_as_uint(P[pmax].w);
      const int c2 = (cmin == tid) ? cmax : cmin;
      par = (short)c2;
      const bool dup = (Wl[c2] == w); // same undirected edge <=> same key
      if (!dup || tid < c2)
        wsum = __uint_as_float((unsigned)((w >> 20) & 0xFFFFFFFFull));
    }
    parentL[tid] = par;
    __syncthreads();
    { // break 2-cycles: smaller index becomes root (pairwise-exclusive race)
      const int p = parentL[tid];
      if (p != tid && parentL[p] == tid && tid < p) parentL[tid] = (short)tid;
    }
    __syncthreads();
    { // chase to roots (forest after 2-cycle break)
      int p = parentL[tid];
      for (int it = 0; it < 1024 && parentL[p] != p; ++it) p = parentL[p];
      rootL[tid] = (short)p;
    }
    __syncthreads();
    const int newlab = rootL[(int)__float_as_uint(P[tid].w)];
    float fc = (newlab == tid) ? 1.f : 0.f;   // roots keep their own index
    block_sum2(wsum, fc, red);
    P[tid].w = __uint_as_float((unsigned)newlab);
    total += wsum;
    if (fc == 1.f) break;             // uniform: combine is deterministic
  }

  // ---- per-sample total -> global accumulator; last finisher writes out ----
  if (part == 0 && tid == 0) {
    atomicAdd(acc, total);
    const int old =
        __hip_atomic_fetch_add(done, 1, __ATOMIC_ACQ_REL, __HIP_MEMORY_SCOPE_AGENT);
    if (old == NSAMP - 1) {
      const float t =
          __hip_atomic_load(acc, __ATOMIC_ACQUIRE, __HIP_MEMORY_SCOPE_AGENT);
      __hip_atomic_store(out, t * (1.f / NSAMP), __ATOMIC_RELAXED,
                         __HIP_MEMORY_SCOPE_SYSTEM);
    }
  }
}

extern "C" void kernel_launch(void* const* d_in, const int* in_sizes, int n_in,
                              void* d_out, int out_size, void* d_ws, size_t ws_size,
                              hipStream_t stream) {
  const float* r = (const float*)d_in[0];
  float* out = (float*)d_out;
  (void)in_sizes; (void)n_in; (void)out_size; (void)ws_size;

  char* ws = (char*)d_ws;
  int*   bar  = (int*)ws;                    // 32 samples x 128 B
  float* acc  = (float*)(ws + 4096);
  int*   done = (int*)(ws + 4100);
  u64*   gw0  = (u64*)(ws + 8192);           // 256 KiB
  u64*   gw1  = (u64*)(ws + 8192 + NSAMP * NPTS * sizeof(u64));  // 256 KiB

  hipMemsetAsync(ws, 0, 4160, stream);       // bar + acc + done
  topo_kernel<<<dim3(NSAMP * SBLK), dim3(TPB), 0, stream>>>(
      r, gw0, gw1, bar, acc, done, out);
}